// Round 11
// baseline (17.820 us; speedup 1.0000x reference)
//
#include <hip/hip_runtime.h>

#define H 512
#define W 512
#define N (H * W)
#define INF_SQ 524289.0f  // H*H + W*W + 1, matches reference INF
#define KA_BLOCKS 256     // 256 threads x 4 pixels (float4) each
#define KB_BLOCKS 512     // 128 threads each, float4

// K_A: direct 2D EDT, 4 pixels/thread. Branchless ring-1 from 3 float4 row
// loads + 6 clamped edge scalars; exact Chebyshev ring loop for r>=2
// (after ring 1, any zero at ring r>=2 has d^2 >= 4, so `r*r < best` is exact).
__global__ __launch_bounds__(256)
void edt2d_k(const float* __restrict__ masks, float* __restrict__ dis,
             float* __restrict__ pmaxm, float* __restrict__ pmaxd) {
    const int tid = blockIdx.x * 256 + threadIdx.x;  // 0..65535
    const int y = tid >> 7;           // row (128 float4 per row)
    const int q = tid & 127;          // float4 index within row
    const int x0 = q << 2;            // first of 4 columns

    const float4* m4 = (const float4*)masks;
    const int yu = (y > 0) ? y - 1 : 0;
    const int yd = (y < H - 1) ? y + 1 : H - 1;

    const float4 u4 = m4[(yu << 7) + q];
    const float4 c4 = m4[(y << 7) + q];
    const float4 d4 = m4[(yd << 7) + q];

    const int xl = (x0 > 0) ? x0 - 1 : 0;
    const int xr = (x0 + 4 < W) ? x0 + 4 : W - 1;
    const float ul = masks[yu * W + xl], ur = masks[yu * W + xr];
    const float cl = masks[y * W + xl],  cr = masks[y * W + xr];
    const float dl = masks[yd * W + xl], dr = masks[yd * W + xr];

    const bool vy0 = (y > 0), vy1 = (y < H - 1);
    const bool vx0 = (x0 > 0), vx1 = (x0 + 4 < W);

    // 6-wide row windows: index k = column x0 + k - 1
    const float rowU[6] = {ul, u4.x, u4.y, u4.z, u4.w, ur};
    const float rowC[6] = {cl, c4.x, c4.y, c4.z, c4.w, cr};
    const float rowD[6] = {dl, d4.x, d4.y, d4.z, d4.w, dr};

    float best[4];
#pragma unroll
    for (int j = 0; j < 4; ++j) {
        const bool lv = (j > 0) || vx0;
        const bool rv = (j < 3) || vx1;
        float b = INF_SQ;
        b = fminf(b, (vy0 && lv && rowU[j] == 0.0f)     ? 2.0f : INF_SQ);
        b = fminf(b, (vy0 &&       rowU[j + 1] == 0.0f) ? 1.0f : INF_SQ);
        b = fminf(b, (vy0 && rv && rowU[j + 2] == 0.0f) ? 2.0f : INF_SQ);
        b = fminf(b, (lv &&        rowC[j] == 0.0f)     ? 1.0f : INF_SQ);
        b = fminf(b, (rv &&        rowC[j + 2] == 0.0f) ? 1.0f : INF_SQ);
        b = fminf(b, (vy1 && lv && rowD[j] == 0.0f)     ? 2.0f : INF_SQ);
        b = fminf(b, (vy1 &&       rowD[j + 1] == 0.0f) ? 1.0f : INF_SQ);
        b = fminf(b, (vy1 && rv && rowD[j + 2] == 0.0f) ? 2.0f : INF_SQ);
        best[j] = (rowC[j + 1] == 0.0f) ? 0.0f : b;
    }

    // exact general ring loop per pixel (rarely entered)
#pragma unroll
    for (int j = 0; j < 4; ++j) {
        const int x = x0 + j;
        float b = best[j];
        for (int r = 2; (float)(r * r) < b; ++r) {
            const int rr = r * r;
            const int ymr = y - r, ypr = y + r;
            const int xa = max(x - r, 0), xb = min(x + r, W - 1);
            if (ymr >= 0) {
                const float* row = masks + ymr * W;
                for (int x2 = xa; x2 <= xb; ++x2)
                    if (row[x2] == 0.0f) {
                        const int dx = x2 - x;
                        b = fminf(b, (float)(dx * dx + rr));
                    }
            }
            if (ypr < H) {
                const float* row = masks + ypr * W;
                for (int x2 = xa; x2 <= xb; ++x2)
                    if (row[x2] == 0.0f) {
                        const int dx = x2 - x;
                        b = fminf(b, (float)(dx * dx + rr));
                    }
            }
            const int y0 = max(y - r + 1, 0), y1 = min(y + r - 1, H - 1);
            if (x - r >= 0) {
                for (int y2 = y0; y2 <= y1; ++y2)
                    if (masks[y2 * W + x - r] == 0.0f) {
                        const int dy = y2 - y;
                        b = fminf(b, (float)(dy * dy + rr));
                    }
            }
            if (x + r < W) {
                for (int y2 = y0; y2 <= y1; ++y2)
                    if (masks[y2 * W + x + r] == 0.0f) {
                        const int dy = y2 - y;
                        b = fminf(b, (float)(dy * dy + rr));
                    }
            }
        }
        best[j] = b;
    }

    float4 o;
    o.x = sqrtf(best[0]); o.y = sqrtf(best[1]);
    o.z = sqrtf(best[2]); o.w = sqrtf(best[3]);
    ((float4*)dis)[tid] = o;

    // block partial maxes (masks center pixels + dis)
    float mm = fmaxf(fmaxf(c4.x, c4.y), fmaxf(c4.z, c4.w));
    float md = fmaxf(fmaxf(o.x, o.y), fmaxf(o.z, o.w));
    for (int off = 32; off > 0; off >>= 1) {
        mm = fmaxf(mm, __shfl_down(mm, off, 64));
        md = fmaxf(md, __shfl_down(md, off, 64));
    }
    __shared__ float sm[4], sd[4];
    const int w = threadIdx.x >> 6, lane = threadIdx.x & 63;
    if (lane == 0) { sm[w] = mm; sd[w] = md; }
    __syncthreads();
    if (threadIdx.x == 0) {
        for (int i = 1; i < 4; ++i) { mm = fmaxf(mm, sm[i]); md = fmaxf(md, sd[i]); }
        pmaxm[blockIdx.x] = mm;
        pmaxd[blockIdx.x] = md;
    }
}

// K_B: every block redundantly reduces the 256+256 partials, then
// normalizes its slice (float4).
__global__ __launch_bounds__(128)
void finalize_k(const float* __restrict__ masks,
                const float* __restrict__ pmaxm,
                const float* __restrict__ pmaxd,
                float* __restrict__ out) {
    const int t = threadIdx.x;

    float mm = fmaxf(pmaxm[t], pmaxm[t + 128]);
    float md = fmaxf(pmaxd[t], pmaxd[t + 128]);
    for (int off = 32; off > 0; off >>= 1) {
        mm = fmaxf(mm, __shfl_down(mm, off, 64));
        md = fmaxf(md, __shfl_down(md, off, 64));
    }
    __shared__ float sm[2], sd[2];
    if ((t & 63) == 0) { sm[t >> 6] = mm; sd[t >> 6] = md; }
    __syncthreads();
    const float maxm = fmaxf(sm[0], sm[1]);
    const float maxd = fmaxf(sd[0], sd[1]);

    const int i = blockIdx.x * 128 + t;  // float4 index; 512*128 = N/4
    const float4 dd = ((const float4*)out)[i];
    const float4 m4 = ((const float4*)masks)[i];
    float4 sk, bd;
    sk.x = dd.x / maxd; sk.y = dd.y / maxd; sk.z = dd.z / maxd; sk.w = dd.w / maxd;
    bd.x = m4.x / maxm - sk.x; bd.y = m4.y / maxm - sk.y;
    bd.z = m4.z / maxm - sk.z; bd.w = m4.w / maxm - sk.w;
    ((float4*)out)[i] = sk;            // skeleton
    ((float4*)out)[N / 4 + i] = bd;    // boundary
}

extern "C" void kernel_launch(void* const* d_in, const int* in_sizes, int n_in,
                              void* d_out, int out_size, void* d_ws, size_t ws_size,
                              hipStream_t stream) {
    const float* masks = (const float*)d_in[0];
    float* out = (float*)d_out;
    float* pmaxm = (float*)d_ws;          // KA_BLOCKS floats
    float* pmaxd = pmaxm + KA_BLOCKS;     // KA_BLOCKS floats

    hipLaunchKernelGGL(edt2d_k, dim3(KA_BLOCKS), dim3(256), 0, stream, masks, out, pmaxm, pmaxd);
    hipLaunchKernelGGL(finalize_k, dim3(KB_BLOCKS), dim3(128), 0, stream, masks, pmaxm, pmaxd, out);
}

// Round 12
// 12.427 us; speedup vs baseline: 1.4339x; 1.4339x over previous
//
#include <hip/hip_runtime.h>

#define H 512
#define W 512
#define N (H * W)
#define INF_SQ 524289.0f  // H*H + W*W + 1, matches reference INF
#define KA_BLOCKS 1024    // 256 threads each, 1 pixel/thread
#define KB_BLOCKS 512     // 128 threads each, float4

// K_A: direct 2D EDT. Ring-1 via 3 center loads + lane shuffles (wave = 64
// consecutive x in one row), exact Chebyshev ring loop for r>=2.
//   best(p) = min over zero pixels q of ||p-q||^2. After ring 1, any zero
//   at ring r>=2 has d^2 >= 4, so the guard r*r < best stays exact.
__global__ __launch_bounds__(256)
void edt2d_k(const float* __restrict__ masks, float* __restrict__ dis,
             float* __restrict__ pmaxm, float* __restrict__ pmaxd) {
    const int idx = blockIdx.x * 256 + threadIdx.x;
    const int y = idx >> 9, x = idx & (W - 1);
    const int lane = threadIdx.x & 63;   // == x & 63 (block = half row)

    const int yu = (y > 0) ? y - 1 : 0;
    const int yd = (y < H - 1) ? y + 1 : H - 1;

    // 3 center-column loads; neighbors via wave shuffles
    const float u = masks[yu * W + x];
    const float c = masks[y * W + x];
    const float d = masks[yd * W + x];

    float ul = __shfl_up(u, 1, 64);
    float cl = __shfl_up(c, 1, 64);
    float dl = __shfl_up(d, 1, 64);
    if (lane == 0) {                      // wave-left boundary: 3 masked loads
        const int xl = (x > 0) ? x - 1 : 0;
        ul = masks[yu * W + xl];
        cl = masks[y * W + xl];
        dl = masks[yd * W + xl];
    }
    float ur = __shfl_down(u, 1, 64);
    float cr = __shfl_down(c, 1, 64);
    float dr = __shfl_down(d, 1, 64);
    if (lane == 63) {                     // wave-right boundary: 3 masked loads
        const int xr = (x < W - 1) ? x + 1 : W - 1;
        ur = masks[yu * W + xr];
        cr = masks[y * W + xr];
        dr = masks[yd * W + xr];
    }

    const bool vy0 = (y > 0), vy1 = (y < H - 1);
    const bool vx0 = (x > 0), vx1 = (x < W - 1);

    float best = INF_SQ;
    best = fminf(best, (vy0 && vx0 && ul == 0.0f) ? 2.0f : INF_SQ);
    best = fminf(best, (vy0 &&        u == 0.0f) ? 1.0f : INF_SQ);
    best = fminf(best, (vy0 && vx1 && ur == 0.0f) ? 2.0f : INF_SQ);
    best = fminf(best, (vx0 &&        cl == 0.0f) ? 1.0f : INF_SQ);
    best = fminf(best, (vx1 &&        cr == 0.0f) ? 1.0f : INF_SQ);
    best = fminf(best, (vy1 && vx0 && dl == 0.0f) ? 2.0f : INF_SQ);
    best = fminf(best, (vy1 &&        d == 0.0f) ? 1.0f : INF_SQ);
    best = fminf(best, (vy1 && vx1 && dr == 0.0f) ? 2.0f : INF_SQ);
    best = (c == 0.0f) ? 0.0f : best;

    // exact general ring loop, r >= 2 (rarely entered)
    for (int r = 2; (float)(r * r) < best; ++r) {
        const int rr = r * r;
        const int ymr = y - r, ypr = y + r;
        const int x0 = max(x - r, 0), x1 = min(x + r, W - 1);
        if (ymr >= 0) {
            const float* row = masks + ymr * W;
            for (int x2 = x0; x2 <= x1; ++x2)
                if (row[x2] == 0.0f) {
                    const int dx = x2 - x;
                    best = fminf(best, (float)(dx * dx + rr));
                }
        }
        if (ypr < H) {
            const float* row = masks + ypr * W;
            for (int x2 = x0; x2 <= x1; ++x2)
                if (row[x2] == 0.0f) {
                    const int dx = x2 - x;
                    best = fminf(best, (float)(dx * dx + rr));
                }
        }
        const int y0 = max(y - r + 1, 0), y1 = min(y + r - 1, H - 1);
        if (x - r >= 0) {
            for (int y2 = y0; y2 <= y1; ++y2)
                if (masks[y2 * W + x - r] == 0.0f) {
                    const int dy = y2 - y;
                    best = fminf(best, (float)(dy * dy + rr));
                }
        }
        if (x + r < W) {
            for (int y2 = y0; y2 <= y1; ++y2)
                if (masks[y2 * W + x + r] == 0.0f) {
                    const int dy = y2 - y;
                    best = fminf(best, (float)(dy * dy + rr));
                }
        }
    }

    const float dd = sqrtf(best);
    dis[idx] = dd;

    // block partial maxes
    float mm = c, md = dd;
    for (int off = 32; off > 0; off >>= 1) {
        mm = fmaxf(mm, __shfl_down(mm, off, 64));
        md = fmaxf(md, __shfl_down(md, off, 64));
    }
    __shared__ float sm[4], sd[4];
    const int w = threadIdx.x >> 6;
    if (lane == 0) { sm[w] = mm; sd[w] = md; }
    __syncthreads();
    if (threadIdx.x == 0) {
        for (int i = 1; i < 4; ++i) { mm = fmaxf(mm, sm[i]); md = fmaxf(md, sd[i]); }
        pmaxm[blockIdx.x] = mm;
        pmaxd[blockIdx.x] = md;
    }
}

// K_B: every block redundantly reduces the 1024+1024 partials, then
// normalizes its slice (float4).
__global__ __launch_bounds__(128)
void finalize_k(const float* __restrict__ masks,
                const float* __restrict__ pmaxm,
                const float* __restrict__ pmaxd,
                float* __restrict__ out) {
    const int t = threadIdx.x;

    float mm = 0.0f, md = 0.0f;
#pragma unroll
    for (int i = 0; i < KA_BLOCKS / 128; ++i) {
        mm = fmaxf(mm, pmaxm[t + i * 128]);
        md = fmaxf(md, pmaxd[t + i * 128]);
    }
    for (int off = 32; off > 0; off >>= 1) {
        mm = fmaxf(mm, __shfl_down(mm, off, 64));
        md = fmaxf(md, __shfl_down(md, off, 64));
    }
    __shared__ float sm[2], sd[2];
    if ((t & 63) == 0) { sm[t >> 6] = mm; sd[t >> 6] = md; }
    __syncthreads();
    const float maxm = fmaxf(sm[0], sm[1]);
    const float maxd = fmaxf(sd[0], sd[1]);

    const int i = blockIdx.x * 128 + t;  // float4 index; 512*128 = N/4
    const float4 d4 = ((const float4*)out)[i];
    const float4 m4 = ((const float4*)masks)[i];
    float4 sk, bd;
    sk.x = d4.x / maxd; sk.y = d4.y / maxd; sk.z = d4.z / maxd; sk.w = d4.w / maxd;
    bd.x = m4.x / maxm - sk.x; bd.y = m4.y / maxm - sk.y;
    bd.z = m4.z / maxm - sk.z; bd.w = m4.w / maxm - sk.w;
    ((float4*)out)[i] = sk;            // skeleton
    ((float4*)out)[N / 4 + i] = bd;    // boundary
}

extern "C" void kernel_launch(void* const* d_in, const int* in_sizes, int n_in,
                              void* d_out, int out_size, void* d_ws, size_t ws_size,
                              hipStream_t stream) {
    const float* masks = (const float*)d_in[0];
    float* out = (float*)d_out;
    float* pmaxm = (float*)d_ws;          // KA_BLOCKS floats
    float* pmaxd = pmaxm + KA_BLOCKS;     // KA_BLOCKS floats

    hipLaunchKernelGGL(edt2d_k, dim3(KA_BLOCKS), dim3(256), 0, stream, masks, out, pmaxm, pmaxd);
    hipLaunchKernelGGL(finalize_k, dim3(KB_BLOCKS), dim3(128), 0, stream, masks, pmaxm, pmaxd, out);
}